// Round 2
// baseline (512.107 us; speedup 1.0000x reference)
//
#include <hip/hip_runtime.h>

#define NUM_CLASSES 8

// Exact argmax over one float4 (first index wins ties, like jnp.argmax).
__device__ __forceinline__ void quad_argmax(const float4 q, float& lv, int& li)
{
    float m01 = q.x; int i01 = 0;
    if (q.y > m01) { m01 = q.y; i01 = 1; }
    float m23 = q.z; int i23 = 2;
    if (q.w > m23) { m23 = q.w; i23 = 3; }
    lv = m01; li = i01;
    if (m23 > lv) { lv = m23; li = i23; }
}

// Lanes 2k and 2k+1 hold the two halves of one row. Exchange (val, idx) with
// the partner lane (lane ^ 1) and resolve exactly: larger value wins; on equal
// value the smaller global element index wins (reference first-wins tie rule).
__device__ __forceinline__ int pair_combine(float lv, int gi)
{
    float pv = __shfl_xor(lv, 1);
    int   pgi = __shfl_xor(gi, 1);
    bool take = (pv > lv) || (pv == lv && pgi < gi);
    return take ? pgi : gi;
}

__global__ __launch_bounds__(256) void confusion_matrix_kernel(
    const float4* __restrict__ t4,
    const float4* __restrict__ p4,
    float* __restrict__ out,
    unsigned int nf)   // float4 count per tensor = 2 * n_rows (always even)
{
    __shared__ unsigned int hist[NUM_CLASSES * NUM_CLASSES];
    for (int i = threadIdx.x; i < NUM_CLASSES * NUM_CLASSES; i += 256)
        hist[i] = 0u;
    __syncthreads();

    const unsigned int tid = blockIdx.x * blockDim.x + threadIdx.x;
    const unsigned int S = gridDim.x * blockDim.x;
    const bool is_even = (threadIdx.x & 1u) == 0u;
    const int hbase = (int)((threadIdx.x & 1u) << 2);  // element offset of my half: 0 or 4

    // Main loop: 4 dense float4s per tensor per iteration (8 dwordx4 in flight).
    // Trip count is wave-uniform, so shuffle partners stay jointly active.
    const unsigned int iters = nf / (4u * S);
    unsigned int f = tid;
    for (unsigned int k = 0; k < iters; ++k) {
        float4 tq0 = t4[f];
        float4 pq0 = p4[f];
        float4 tq1 = t4[f + S];
        float4 pq1 = p4[f + S];
        float4 tq2 = t4[f + 2u * S];
        float4 pq2 = p4[f + 2u * S];
        float4 tq3 = t4[f + 3u * S];
        float4 pq3 = p4[f + 3u * S];

        float tv; int tiL; float pv; int piL; int ti; int pi;

        quad_argmax(tq0, tv, tiL); quad_argmax(pq0, pv, piL);
        ti = pair_combine(tv, hbase + tiL);
        pi = pair_combine(pv, hbase + piL);
        if (is_even) atomicAdd(&hist[ti * NUM_CLASSES + pi], 1u);

        quad_argmax(tq1, tv, tiL); quad_argmax(pq1, pv, piL);
        ti = pair_combine(tv, hbase + tiL);
        pi = pair_combine(pv, hbase + piL);
        if (is_even) atomicAdd(&hist[ti * NUM_CLASSES + pi], 1u);

        quad_argmax(tq2, tv, tiL); quad_argmax(pq2, pv, piL);
        ti = pair_combine(tv, hbase + tiL);
        pi = pair_combine(pv, hbase + piL);
        if (is_even) atomicAdd(&hist[ti * NUM_CLASSES + pi], 1u);

        quad_argmax(tq3, tv, tiL); quad_argmax(pq3, pv, piL);
        ti = pair_combine(tv, hbase + tiL);
        pi = pair_combine(pv, hbase + piL);
        if (is_even) atomicAdd(&hist[ti * NUM_CLASSES + pi], 1u);

        f += 4u * S;
    }

    // Remainder: nf is even, so lane pairs (2k,2k+1) drop out together and
    // shuffle partners remain jointly active.
    for (; f < nf; f += S) {
        float4 tq = t4[f];
        float4 pq = p4[f];
        float tv; int tiL; quad_argmax(tq, tv, tiL);
        float pv; int piL; quad_argmax(pq, pv, piL);
        int ti = pair_combine(tv, hbase + tiL);
        int pi = pair_combine(pv, hbase + piL);
        if (is_even) atomicAdd(&hist[ti * NUM_CLASSES + pi], 1u);
    }

    __syncthreads();
    for (int i = threadIdx.x; i < NUM_CLASSES * NUM_CLASSES; i += 256) {
        unsigned int v = hist[i];
        if (v) atomicAdd(&out[i], (float)v);
    }
}

extern "C" void kernel_launch(void* const* d_in, const int* in_sizes, int n_in,
                              void* d_out, int out_size, void* d_ws, size_t ws_size,
                              hipStream_t stream)
{
    const float4* y_true = (const float4*)d_in[0];
    const float4* y_pred = (const float4*)d_in[1];
    float* out = (float*)d_out;

    const int n = in_sizes[0] / NUM_CLASSES;          // 8388608 rows
    const unsigned int nf = (unsigned int)n * 2u;     // float4s per tensor

    // Harness re-poisons d_out with 0xAA before every timed replay: zero it.
    hipMemsetAsync(out, 0, (size_t)out_size * sizeof(float), stream);

    const int block = 256;
    const int grid = 2048;  // 8 blocks/CU exactly; 8 iterations/thread
    confusion_matrix_kernel<<<grid, block, 0, stream>>>(y_true, y_pred, out, nf);
}

// Round 3
// 502.226 us; speedup vs baseline: 1.0197x; 1.0197x over previous
//
#include <hip/hip_runtime.h>

#define NUM_CLASSES 8

// Exact argmax over one 8-float row (first index wins ties, like jnp.argmax).
__device__ __forceinline__ int row_argmax(const float4 a, const float4 b)
{
    float m = a.x; int i = 0;
    if (a.y > m) { m = a.y; i = 1; }
    if (a.z > m) { m = a.z; i = 2; }
    if (a.w > m) { m = a.w; i = 3; }
    if (b.x > m) { m = b.x; i = 4; }
    if (b.y > m) { m = b.y; i = 5; }
    if (b.z > m) { m = b.z; i = 6; }
    if (b.w > m) { m = b.w; i = 7; }
    return i;
}

__global__ __launch_bounds__(256) void confusion_matrix_kernel(
    const float4* __restrict__ t4,
    const float4* __restrict__ p4,
    float* __restrict__ out,
    unsigned int nrows)
{
    __shared__ unsigned int hist[NUM_CLASSES * NUM_CLASSES];
    if (threadIdx.x < NUM_CLASSES * NUM_CLASSES) hist[threadIdx.x] = 0u;
    __syncthreads();

    // Block-linear partitioning: block b owns a CONTIGUOUS slab of rows.
    // rpb rounded up to an even number so coverage is complete for any nrows.
    const unsigned int rpb =
        (((nrows + gridDim.x - 1u) / gridDim.x) + 1u) & ~1u;
    const unsigned int row0 = blockIdx.x * rpb;
    unsigned int row_end = row0 + rpb;
    if (row_end > nrows) row_end = nrows;

    // Each step: 256 threads x 2 adjacent rows = 512 contiguous rows (16 KiB
    // per tensor, sequential sweep through the slab). 8 dwordx4 in flight
    // per thread; VGPR stays <= 64 so all 8 waves/SIMD remain resident.
    for (unsigned int r = row0 + threadIdx.x * 2u; r < row_end; r += 512u) {
        const unsigned int q = 2u * r;            // float4 index of row r
        const bool have2 = (r + 1u) < row_end;

        float4 ta0 = t4[q + 0u];
        float4 ta1 = t4[q + 1u];
        float4 pa0 = p4[q + 0u];
        float4 pa1 = p4[q + 1u];
        // Second row of the pair (guarded; uniform-true for the bench shape).
        float4 tb0, tb1, pb0, pb1;
        if (have2) {
            tb0 = t4[q + 2u];
            tb1 = t4[q + 3u];
            pb0 = p4[q + 2u];
            pb1 = p4[q + 3u];
        }

        const int ti0 = row_argmax(ta0, ta1);
        const int pi0 = row_argmax(pa0, pa1);
        atomicAdd(&hist[ti0 * NUM_CLASSES + pi0], 1u);

        if (have2) {
            const int ti1 = row_argmax(tb0, tb1);
            const int pi1 = row_argmax(pb0, pb1);
            atomicAdd(&hist[ti1 * NUM_CLASSES + pi1], 1u);
        }
    }

    __syncthreads();
    if (threadIdx.x < NUM_CLASSES * NUM_CLASSES) {
        const unsigned int v = hist[threadIdx.x];
        if (v) atomicAdd(&out[threadIdx.x], (float)v);
    }
}

extern "C" void kernel_launch(void* const* d_in, const int* in_sizes, int n_in,
                              void* d_out, int out_size, void* d_ws, size_t ws_size,
                              hipStream_t stream)
{
    const float4* y_true = (const float4*)d_in[0];
    const float4* y_pred = (const float4*)d_in[1];
    float* out = (float*)d_out;

    const unsigned int nrows = (unsigned int)(in_sizes[0] / NUM_CLASSES);  // 8388608

    // Harness re-poisons d_out with 0xAA before every timed replay: zero it.
    hipMemsetAsync(out, 0, (size_t)out_size * sizeof(float), stream);

    const int block = 256;
    const int grid = 2048;  // 8 blocks/CU; each block sweeps a 4096-row slab
    confusion_matrix_kernel<<<grid, block, 0, stream>>>(y_true, y_pred, out, nrows);
}